// Round 1
// baseline (353.073 us; speedup 1.0000x reference)
//
#include <hip/hip_runtime.h>
#include <hip/hip_bf16.h>
#include <math.h>

#define SEQ 512
#define DM  256
#define NH  8
#define DH  32
#define DD  (DM*DM)   // 65536

typedef __attribute__((ext_vector_type(4))) float  f32x4;
typedef __attribute__((ext_vector_type(8))) __bf16 bf16x8;
typedef __attribute__((ext_vector_type(8))) short  s16x8;
typedef __attribute__((ext_vector_type(4))) short  s16x4;

__device__ __forceinline__ unsigned short f2bf(float f) {
  unsigned int u = __builtin_bit_cast(unsigned int, f);
  u += 0x7fffu + ((u >> 16) & 1u);           // round-to-nearest-even
  return (unsigned short)(u >> 16);
}
__device__ __forceinline__ float bf2f(unsigned short h) {
  unsigned int u = ((unsigned int)h) << 16;
  return __builtin_bit_cast(float, u);
}

// ---------------------------------------------------------------------------
// K0: blocks 0..31 convert k (f32->bf16, layout-preserving);
//     blocks 32..63 transpose v -> vT[m][l] bf16 via LDS tiles.
__global__ __launch_bounds__(256) void k0_convert(const float* __restrict__ kin,
                                                  const float* __restrict__ vin,
                                                  unsigned short* __restrict__ kbf,
                                                  unsigned short* __restrict__ vT) {
  __shared__ unsigned short tl[64][72];
  int b = blockIdx.x, t = threadIdx.x;
  if (b < 32) {
    int base = b * 4096 + t * 16;
    float4 a0 = *(const float4*)(kin + base);
    float4 a1 = *(const float4*)(kin + base + 4);
    float4 a2 = *(const float4*)(kin + base + 8);
    float4 a3 = *(const float4*)(kin + base + 12);
    s16x8 o0, o1;
    o0[0]=f2bf(a0.x); o0[1]=f2bf(a0.y); o0[2]=f2bf(a0.z); o0[3]=f2bf(a0.w);
    o0[4]=f2bf(a1.x); o0[5]=f2bf(a1.y); o0[6]=f2bf(a1.z); o0[7]=f2bf(a1.w);
    o1[0]=f2bf(a2.x); o1[1]=f2bf(a2.y); o1[2]=f2bf(a2.z); o1[3]=f2bf(a2.w);
    o1[4]=f2bf(a3.x); o1[5]=f2bf(a3.y); o1[6]=f2bf(a3.z); o1[7]=f2bf(a3.w);
    *(s16x8*)(kbf + base)     = o0;
    *(s16x8*)(kbf + base + 8) = o1;
  } else {
    int tb = b - 32;
    int i0 = (tb >> 2) * 64;        // 8 i-tiles
    int m0 = (tb & 3) * 64;         // 4 m-tiles
    int r = t >> 2, cq = t & 3;
    #pragma unroll
    for (int u = 0; u < 4; u++) {
      float4 x = *(const float4*)(vin + (size_t)(i0 + r) * DM + m0 + cq * 16 + u * 4);
      tl[cq*16 + u*4 + 0][r] = f2bf(x.x);
      tl[cq*16 + u*4 + 1][r] = f2bf(x.y);
      tl[cq*16 + u*4 + 2][r] = f2bf(x.z);
      tl[cq*16 + u*4 + 3][r] = f2bf(x.w);
    }
    __syncthreads();
    int mm = t >> 2;
    s16x8 w0, w1;
    #pragma unroll
    for (int e = 0; e < 8; e++) { w0[e] = tl[mm][cq*16 + e]; w1[e] = tl[mm][cq*16 + 8 + e]; }
    *(s16x8*)(vT + (size_t)(m0 + mm) * SEQ + i0 + cq * 16)     = w0;
    *(s16x8*)(vT + (size_t)(m0 + mm) * SEQ + i0 + cq * 16 + 8) = w1;
  }
}

// ---------------------------------------------------------------------------
// K1: qp = q @ Wq^T  (one block per row i; wave-per-output-dot, shuffle reduce)
__global__ __launch_bounds__(256) void k1_qproj(const float* __restrict__ q,
                                                const float* __restrict__ Wq,
                                                float* __restrict__ qpf,
                                                unsigned short* __restrict__ qpb) {
  __shared__ __align__(16) float qrow[DM];
  int i = blockIdx.x, t = threadIdx.x;
  if (t < 64) *(float4*)&qrow[t*4] = *(const float4*)(q + (size_t)i * DM + t * 4);
  __syncthreads();
  int w = t >> 6, lane = t & 63;
  for (int jj = 0; jj < 64; jj++) {
    int j = w * 64 + jj;
    float4 wv = *(const float4*)(Wq + (size_t)j * DM + lane * 4);
    float s = wv.x*qrow[lane*4] + wv.y*qrow[lane*4+1] + wv.z*qrow[lane*4+2] + wv.w*qrow[lane*4+3];
    #pragma unroll
    for (int off = 32; off; off >>= 1) s += __shfl_xor(s, off);
    if (lane == 0) { qpf[(size_t)i*DM + j] = s; qpb[(size_t)i*DM + j] = f2bf(s); }
  }
}

// ---------------------------------------------------------------------------
// Generic NT bf16 MFMA GEMM: C[M,N] = A[M,K] * B[N,K]^T
// CONVB: B is f32 in global, converted to bf16 during staging.
// OUTBF: store C as bf16 (else f32).
// BM=BN=128, BK=64, 4 waves (2x2), 4x4 16x16x32 frags per wave.
// LDS row stride 72 bf16 (pad 8) -> even bank histogram for ds_read_b128.
template<int CONVB, int OUTBF>
__global__ __launch_bounds__(256) void gemm_nt(const unsigned short* __restrict__ A,
                                               const void* __restrict__ Bp,
                                               void* __restrict__ Cp,
                                               int M, int N, int K, int nMtiles) {
  __shared__ __align__(16) unsigned short lA[128 * 72];
  __shared__ __align__(16) unsigned short lB[128 * 72];
  int bid = blockIdx.x;
  int mtile = bid % nMtiles, ntile = bid / nMtiles;
  int m0 = mtile * 128, n0 = ntile * 128;
  int t = threadIdx.x;
  int w = t >> 6, lane = t & 63;
  int wr = w >> 1, wc = w & 1;
  f32x4 acc[4][4];
  #pragma unroll
  for (int a = 0; a < 4; a++)
    #pragma unroll
    for (int b = 0; b < 4; b++) acc[a][b] = (f32x4){0.f, 0.f, 0.f, 0.f};

  for (int kt = 0; kt < K; kt += 64) {
    __syncthreads();
    #pragma unroll
    for (int rep = 0; rep < 4; rep++) {      // stage A tile (bf16 passthrough)
      int sc = rep * 256 + t;
      int row = sc >> 3, c8 = sc & 7;
      *(s16x8*)&lA[row*72 + c8*8] = *(const s16x8*)(A + (size_t)(m0+row)*K + kt + c8*8);
    }
    if (CONVB) {                              // stage B tile with f32->bf16
      const float* B = (const float*)Bp;
      #pragma unroll
      for (int rep = 0; rep < 4; rep++) {
        int sc = rep * 256 + t;
        int row = sc >> 3, c8 = sc & 7;
        const float* src = B + (size_t)(n0+row)*K + kt + c8*8;
        float4 u0 = *(const float4*)src;
        float4 u1 = *(const float4*)(src + 4);
        s16x8 o;
        o[0]=f2bf(u0.x); o[1]=f2bf(u0.y); o[2]=f2bf(u0.z); o[3]=f2bf(u0.w);
        o[4]=f2bf(u1.x); o[5]=f2bf(u1.y); o[6]=f2bf(u1.z); o[7]=f2bf(u1.w);
        *(s16x8*)&lB[row*72 + c8*8] = o;
      }
    } else {
      const unsigned short* B = (const unsigned short*)Bp;
      #pragma unroll
      for (int rep = 0; rep < 4; rep++) {
        int sc = rep * 256 + t;
        int row = sc >> 3, c8 = sc & 7;
        *(s16x8*)&lB[row*72 + c8*8] = *(const s16x8*)(B + (size_t)(n0+row)*K + kt + c8*8);
      }
    }
    __syncthreads();
    #pragma unroll
    for (int kk = 0; kk < 2; kk++) {
      int r = lane & 15, kc = kk*32 + (lane >> 4)*8;
      bf16x8 af[4], bfv[4];
      #pragma unroll
      for (int mf = 0; mf < 4; mf++) af[mf]  = *(const bf16x8*)&lA[(wr*64 + mf*16 + r)*72 + kc];
      #pragma unroll
      for (int nf = 0; nf < 4; nf++) bfv[nf] = *(const bf16x8*)&lB[(wc*64 + nf*16 + r)*72 + kc];
      #pragma unroll
      for (int mf = 0; mf < 4; mf++)
        #pragma unroll
        for (int nf = 0; nf < 4; nf++)
          acc[mf][nf] = __builtin_amdgcn_mfma_f32_16x16x32_bf16(af[mf], bfv[nf], acc[mf][nf], 0, 0, 0);
    }
  }
  // C/D layout (m89-verified): col = lane&15, row = (lane>>4)*4 + reg
  int cr = (lane >> 4) * 4, cc = lane & 15;
  #pragma unroll
  for (int mf = 0; mf < 4; mf++)
    #pragma unroll
    for (int nf = 0; nf < 4; nf++)
      #pragma unroll
      for (int qq = 0; qq < 4; qq++) {
        int row = m0 + wr*64 + mf*16 + cr + qq;
        int col = n0 + wc*64 + nf*16 + cc;
        float vv = acc[mf][nf][qq];
        if (OUTBF) ((unsigned short*)Cp)[(size_t)row * N + col] = f2bf(vv);
        else       ((float*)Cp)[(size_t)row * N + col] = vv;
      }
}

// ---------------------------------------------------------------------------
// K3: a[n,i,k] = sum_{j in head n} qp[i, n*32+j] * Pk[i, (n*32+j)*256 + k]
// block per i; wave owns 2 heads; 2 j-rows per load pass; xor(32) combine.
__global__ __launch_bounds__(256) void k3_reduce_a(const unsigned short* __restrict__ Pk,
                                                   const float* __restrict__ qpf,
                                                   unsigned short* __restrict__ abf) {
  __shared__ __align__(16) float ql[DM];
  int i = blockIdx.x, t = threadIdx.x;
  if (t < 64) *(float4*)&ql[t*4] = *(const float4*)(qpf + (size_t)i * DM + t * 4);
  __syncthreads();
  int w = t >> 6, lane = t & 63;
  const unsigned short* Prow = Pk + (size_t)i * DD;
  #pragma unroll
  for (int h = 0; h < 2; h++) {
    int n = w * 2 + h;
    float acc[8] = {0,0,0,0,0,0,0,0};
    for (int js = 0; js < 32; js += 2) {
      int j = n * 32 + js + (lane >> 5);
      s16x8 pv = *(const s16x8*)(Prow + (size_t)j * 256 + (lane & 31) * 8);
      float qv = ql[j];
      #pragma unroll
      for (int e = 0; e < 8; e++) acc[e] += qv * bf2f((unsigned short)pv[e]);
    }
    #pragma unroll
    for (int e = 0; e < 8; e++) acc[e] += __shfl_xor(acc[e], 32);
    if (lane < 32) {
      s16x8 o;
      #pragma unroll
      for (int e = 0; e < 8; e++) o[e] = f2bf(acc[e]);
      *(s16x8*)(abf + ((size_t)n * SEQ + i) * DM + (lane & 31) * 8) = o;
    }
  }
}

// ---------------------------------------------------------------------------
// K4b: masked softmax over rows of logits[n*512+i][l], causal l<=i, scale 1/sqrt(512)
__global__ __launch_bounds__(256) void k4b_softmax(const float* __restrict__ logits,
                                                   unsigned short* __restrict__ probs) {
  __shared__ float red[4];
  __shared__ float red2[4];
  int m = blockIdx.x, t = threadIdx.x;
  int i = m & (SEQ - 1);
  const float scale = 0.04419417382415922f;   // 1/sqrt(512)
  const float NEG = -1e30f;
  float v0 = (t       <= i) ? logits[(size_t)m * SEQ + t      ] * scale : NEG;
  float v1 = (t + 256 <= i) ? logits[(size_t)m * SEQ + t + 256] * scale : NEG;
  float mx = fmaxf(v0, v1);
  #pragma unroll
  for (int off = 32; off; off >>= 1) mx = fmaxf(mx, __shfl_xor(mx, off));
  int w = t >> 6, lane = t & 63;
  if (lane == 0) red[w] = mx;
  __syncthreads();
  mx = fmaxf(fmaxf(red[0], red[1]), fmaxf(red[2], red[3]));
  float e0 = (t       <= i) ? __expf(v0 - mx) : 0.f;
  float e1 = (t + 256 <= i) ? __expf(v1 - mx) : 0.f;
  float s = e0 + e1;
  #pragma unroll
  for (int off = 32; off; off >>= 1) s += __shfl_xor(s, off);
  if (lane == 0) red2[w] = s;
  __syncthreads();
  s = red2[0] + red2[1] + red2[2] + red2[3];
  float inv = 1.f / s;
  probs[(size_t)m * SEQ + t]       = f2bf(e0 * inv);
  probs[(size_t)m * SEQ + t + 256] = f2bf(e1 * inv);
}

// ---------------------------------------------------------------------------
// K5: out[i,j] = sum_k Pv[i, j*256+k] * w[j>>5, i, k]   (block per i)
__global__ __launch_bounds__(256) void k5_out(const unsigned short* __restrict__ Pv,
                                              const unsigned short* __restrict__ wbf,
                                              float* __restrict__ out) {
  __shared__ __align__(16) float wl[8 * 264];
  int i = blockIdx.x, t = threadIdx.x;
  {
    int n = t >> 5, k8 = (t & 31) * 8;
    s16x8 v = *(const s16x8*)(wbf + ((size_t)n * SEQ + i) * DM + k8);
    #pragma unroll
    for (int e = 0; e < 8; e++) wl[n * 264 + k8 + e] = bf2f((unsigned short)v[e]);
  }
  __syncthreads();
  int w = t >> 6, lane = t & 63;
  const unsigned short* Prow = Pv + (size_t)i * DD;
  for (int jj = 0; jj < 64; jj++) {
    int j = w * 64 + jj;
    int n = j >> 5;
    s16x4 pv = *(const s16x4*)(Prow + (size_t)j * 256 + lane * 4);
    const float* wp = &wl[n * 264 + lane * 4];
    float s = bf2f((unsigned short)pv[0]) * wp[0] + bf2f((unsigned short)pv[1]) * wp[1]
            + bf2f((unsigned short)pv[2]) * wp[2] + bf2f((unsigned short)pv[3]) * wp[3];
    #pragma unroll
    for (int off = 32; off; off >>= 1) s += __shfl_xor(s, off);
    if (lane == 0) out[(size_t)i * DM + j] = s;
  }
}

// ---------------------------------------------------------------------------
extern "C" void kernel_launch(void* const* d_in, const int* in_sizes, int n_in,
                              void* d_out, int out_size, void* d_ws, size_t ws_size,
                              hipStream_t stream) {
  (void)in_sizes; (void)n_in; (void)out_size; (void)ws_size;
  const float* q  = (const float*)d_in[0];
  const float* k  = (const float*)d_in[1];
  const float* v  = (const float*)d_in[2];
  const float* Wq = (const float*)d_in[3];
  const float* Wk = (const float*)d_in[4];
  const float* Wv = (const float*)d_in[5];
  float* out = (float*)d_out;

  char* ws = (char*)d_ws;
  size_t off = 0;
  auto alloc = [&](size_t bytes) -> void* {
    void* p = ws + off; off += (bytes + 255) & ~(size_t)255; return p;
  };
  float*          qpf    = (float*)         alloc((size_t)SEQ * DM * 4);
  unsigned short* qpb    = (unsigned short*)alloc((size_t)SEQ * DM * 2);
  unsigned short* kbf    = (unsigned short*)alloc((size_t)SEQ * DM * 2);
  unsigned short* vT     = (unsigned short*)alloc((size_t)DM * SEQ * 2);
  unsigned short* abf    = (unsigned short*)alloc((size_t)NH * SEQ * DM * 2);
  float*          logits = (float*)         alloc((size_t)NH * SEQ * SEQ * 4);
  unsigned short* probs  = (unsigned short*)alloc((size_t)NH * SEQ * SEQ * 2);
  unsigned short* wbf    = (unsigned short*)alloc((size_t)NH * SEQ * DM * 2);
  unsigned short* Pk     = (unsigned short*)alloc((size_t)SEQ * DD * 2);
  unsigned short* Pv     = (unsigned short*)alloc((size_t)SEQ * DD * 2);
  // total ~146 MiB of d_ws

  k0_convert<<<64, 256, 0, stream>>>(k, v, kbf, vT);
  k1_qproj<<<SEQ, 256, 0, stream>>>(q, Wq, qpf, qpb);
  // Pk/Pv = qp @ W_hyper^T : M=512, N=65536, K=256; nMtiles=4 so the 4 M-tiles
  // sharing one B-tile are consecutive blockIdx (L2/L3 reuse of the f32 weights)
  gemm_nt<1,1><<<2048, 256, 0, stream>>>(qpb, (const void*)Wk, (void*)Pk, SEQ, DD, DM, 4);
  gemm_nt<1,1><<<2048, 256, 0, stream>>>(qpb, (const void*)Wv, (void*)Pv, SEQ, DD, DM, 4);
  k3_reduce_a<<<SEQ, 256, 0, stream>>>(Pk, qpf, abf);
  // logits = a @ k^T : M = 8*512 (n-major rows), N=512, K=256
  gemm_nt<0,0><<<128, 256, 0, stream>>>(abf, (const void*)kbf, (void*)logits, NH*SEQ, SEQ, DM, 32);
  k4b_softmax<<<NH*SEQ, 256, 0, stream>>>(logits, probs);
  // w = probs @ v : M = 8*512, N=256 (k), K=512 (l); B = v^T
  gemm_nt<0,1><<<64, 256, 0, stream>>>(probs, (const void*)vT, (void*)wbf, NH*SEQ, DM, SEQ, 32);
  k5_out<<<SEQ, 256, 0, stream>>>(Pv, wbf, out);
}